// Round 3
// baseline (22.746 us; speedup 1.0000x reference)
//
#include <hip/hip_runtime.h>
#include <math.h>

// PoolingConnection fused: out[k,i,j] = max(s[k, 6i:6i+64, 6j:6j+64]) clipped at 384.
// F=128, H=W=384, stride=6, window=64, out=[128,64,64].
// Grid = (k, quarter): 512 blocks x 512 threads -> 2 blocks/CU.
// Quarters are balanced by INPUT row count (142/136/136/144), so no CU idles
// behind heavy blocks. Phase 1 pools along W (wave-per-row shuffle sliding max)
// into LDS; phase 2 pools along H via 6-row segment maxes (separable again).

constexpr int F  = 128;
constexpr int H  = 384;
constexpr int W  = 384;
constexpr int ST = 6;
constexpr int OH = 64;
constexpr int OW = 64;

constexpr int MAXROWS = 144;  // max input rows per chunk
constexpr int MAXSEG  = 34;   // max H-segments per chunk

#define NINF (-__builtin_huge_valf())

// shuffle value from lane (lane+d); lanes beyond 63 contribute -inf
// (implements the right-edge window clipping for free).
__device__ __forceinline__ float sh_ninf(float v, int lane, int d) {
    float r = __shfl(v, lane + d, 64);
    return (lane + d > 63) ? NINF : r;
}

// Output-row chunks: i0 = {0,14,27,40}, ni = {14,13,13,24}.
// Input rows per chunk: 6*ni+58 clipped at H-6*i0 -> 142,136,136,144.
__global__ __launch_bounds__(512) void pool_fused_kernel(const float* __restrict__ s,
                                                         float* __restrict__ out) {
    __shared__ float rowmax[MAXROWS][64];  // 36 KiB
    __shared__ float segm[MAXSEG][64];     // 8.5 KiB: max of seg rows 0..5
    __shared__ float segp[MAXSEG][64];     // 8.5 KiB: max of seg rows 0..3

    const int q = blockIdx.x & 3;
    const int k = blockIdx.x >> 2;

    const int i0    = (q == 0) ? 0 : (q == 1) ? 14 : (q == 2) ? 27 : 40;
    const int ni    = (q == 0) ? 14 : (q == 3) ? 24 : 13;
    const int rbeg  = i0 * ST;
    const int nrows = min(6 * ni + 58, H - rbeg);  // 142,136,136,144
    const int nseg  = ni + 10;                     // 24,23,23,34

    const int tid  = threadIdx.x;
    const int wv   = tid >> 6;     // 0..7
    const int lane = tid & 63;

    // ---- Phase 1: pool along W, one wave per input row ----
    // Lane l owns cols [6l, 6l+5]. Window j = lane j (6) + lanes j+1..j+9 (6 each)
    // + first 4 of lane j+10.
    const float* srow_base = s + ((size_t)k * H + rbeg) * W + lane * 6;
    for (int rl = wv; rl < nrows; rl += 8) {
        const float* row = srow_base + (size_t)rl * W;
        const float2 e0 = *reinterpret_cast<const float2*>(row);
        const float2 e1 = *reinterpret_cast<const float2*>(row + 2);
        const float2 e2 = *reinterpret_cast<const float2*>(row + 4);

        const float p3 = fmaxf(fmaxf(e0.x, e0.y), fmaxf(e1.x, e1.y)); // first 4
        const float m  = fmaxf(p3, fmaxf(e2.x, e2.y));                // all 6

        const float a1 = fmaxf(m,  sh_ninf(m,  lane, 1));   // [l, l+1]
        const float a2 = fmaxf(a1, sh_ninf(a1, lane, 2));   // [l .. l+3]
        const float a3 = fmaxf(a2, sh_ninf(a2, lane, 4));   // [l .. l+7]
        const float a4 = fmaxf(a3, sh_ninf(a1, lane, 8));   // [l .. l+9]
        const float r  = fmaxf(a4, sh_ninf(p3, lane, 10));  // + 4 of l+10

        rowmax[rl][lane] = r;
    }
    __syncthreads();

    // ---- Phase 2a: 6-row segment maxes along H ----
    // segm[gl] = max rows 6gl..6gl+5, segp[gl] = max rows 6gl..6gl+3,
    // guard r >= nrows -> -inf (bottom clipping).
    for (int job = tid; job < nseg * 64; job += 512) {
        const int gl = job >> 6;
        const int j  = job & 63;
        const int r0 = gl * 6;
        float m6 = NINF, m4 = NINF;
        #pragma unroll
        for (int t = 0; t < 6; ++t) {
            const float v = (r0 + t < nrows) ? rowmax[r0 + t][j] : NINF;
            m6 = fmaxf(m6, v);
            if (t < 4) m4 = fmaxf(m4, v);
        }
        segm[gl][j] = m6;
        segp[gl][j] = m4;
    }
    __syncthreads();

    // ---- Phase 2b: out[i0+li] = max(segm[li..li+9], segp[li+10]) ----
    for (int job = tid; job < ni * 64; job += 512) {
        const int li = job >> 6;
        const int j  = job & 63;
        float acc = segp[li + 10][j];
        #pragma unroll
        for (int t = 0; t < 10; ++t) acc = fmaxf(acc, segm[li + t][j]);
        out[((size_t)k * OH + i0 + li) * OW + j] = acc;   // coalesced
    }
}

extern "C" void kernel_launch(void* const* d_in, const int* in_sizes, int n_in,
                              void* d_out, int out_size, void* d_ws, size_t ws_size,
                              hipStream_t stream) {
    const float* s = (const float*)d_in[0];
    float* out     = (float*)d_out;
    pool_fused_kernel<<<F * 4, 512, 0, stream>>>(s, out);
}

// Round 4
// 18.540 us; speedup vs baseline: 1.2269x; 1.2269x over previous
//
#include <hip/hip_runtime.h>
#include <math.h>

// PoolingConnection fused: out[k,i,j] = max(s[k, 6i:6i+64, 6j:6j+64]) clipped at 384.
// F=128, H=W=384, stride=6, window=64, out=[128,64,64].
//
// Decomposition: H = 64 segments of exactly 6 rows (384 = 64*6).
//   out[i] = max(segm[i..i+9], segp[i+10])          (segments > 63 -> -inf)
//   segm[g] = 2D max over rows 6g..6g+5 (W-pooled), segp[g] = rows 6g..6g+3.
// Reduction order commuted: vertical (6-row, in-register) max FIRST, then one
// shuffle sliding-window per segment -> no rowmax LDS array at all.
//
// Grid = (k, half), 256 blocks x 1024 threads. Halves balanced: both read
// exactly 222 input rows (output rows 0..26 / 27..63, segments 0..36 / 27..63).

constexpr int F  = 128;
constexpr int H  = 384;
constexpr int W  = 384;
constexpr int ST = 6;
constexpr int OH = 64;
constexpr int OW = 64;

constexpr int NSEG   = 37;        // segments per half
constexpr int SEGPAD = NSEG + 10; // padded with -inf for fixed 10-tap combine

#define NINF (-__builtin_huge_valf())

// shuffle value from lane (lane+d); lanes beyond 63 contribute -inf
// (implements the right-edge window clipping for free).
__device__ __forceinline__ float sh_ninf(float v, int lane, int d) {
    float r = __shfl(v, lane + d, 64);
    return (lane + d > 63) ? NINF : r;
}

// sliding max over lanes [l..l+9] of m, plus first-4-cols of lane l+10
__device__ __forceinline__ float slide_window(float m, float p3, int lane) {
    const float a1 = fmaxf(m,  sh_ninf(m,  lane, 1));   // [l, l+1]
    const float a2 = fmaxf(a1, sh_ninf(a1, lane, 2));   // [l .. l+3]
    const float a3 = fmaxf(a2, sh_ninf(a2, lane, 4));   // [l .. l+7]
    const float a4 = fmaxf(a3, sh_ninf(a1, lane, 8));   // [l .. l+9]
    return fmaxf(a4, sh_ninf(p3, lane, 10));            // + 4 cols of l+10
}

__global__ __launch_bounds__(1024) void pool_fused_kernel(const float* __restrict__ s,
                                                          float* __restrict__ out) {
    __shared__ float segm[SEGPAD][64];   // 11.75 KiB
    __shared__ float segp[SEGPAD][64];   // 11.75 KiB

    const int k    = blockIdx.x >> 1;
    const int half = blockIdx.x & 1;

    const int sbeg = half ? 27 : 0;   // first global segment this block computes
    const int obeg = half ? 27 : 0;   // first output row this block produces
    const int ni   = half ? 37 : 27;  // output rows produced

    const int tid  = threadIdx.x;
    const int wv   = tid >> 6;        // 0..15
    const int lane = tid & 63;

    // pad tail segments with -inf (bottom clipping for out i >= 54)
    for (int job = tid; job < 10 * 64; job += 1024) {
        const int g = NSEG + (job >> 6);
        const int j = job & 63;
        segm[g][j] = NINF;
        segp[g][j] = NINF;
    }

    // ---- Phase 1: per-segment 2D partial max ----
    // Lane l owns cols [6l, 6l+5]. For its segment, vertical max over the 6
    // rows in registers, then one shuffle sliding-window pass each for
    // segm (all 6 rows) and segp (first 4 rows).
    const float* base = s + ((size_t)k * H + sbeg * ST) * W + lane * 6;
    for (int gl = wv; gl < NSEG; gl += 16) {
        const float* seg = base + (size_t)gl * ST * W;
        float vm6 = NINF, vp6 = NINF;   // all-6-cols / first-4-cols, rows 0..5
        float vm4 = NINF, vp4 = NINF;   // rows 0..3 only
        #pragma unroll
        for (int t = 0; t < 6; ++t) {
            const float* row = seg + (size_t)t * W;
            const float2 e0 = *reinterpret_cast<const float2*>(row);
            const float2 e1 = *reinterpret_cast<const float2*>(row + 2);
            const float2 e2 = *reinterpret_cast<const float2*>(row + 4);
            const float p3 = fmaxf(fmaxf(e0.x, e0.y), fmaxf(e1.x, e1.y));
            const float m  = fmaxf(p3, fmaxf(e2.x, e2.y));
            vm6 = fmaxf(vm6, m);
            vp6 = fmaxf(vp6, p3);
            if (t < 4) { vm4 = fmaxf(vm4, m); vp4 = fmaxf(vp4, p3); }
        }
        segm[gl][lane] = slide_window(vm6, vp6, lane);
        segp[gl][lane] = slide_window(vm4, vp4, lane);
    }
    __syncthreads();

    // ---- Phase 2: out[obeg+li] = max(segm[li..li+9], segp[li+10]) ----
    // (local seg index == local output index since sbeg == obeg)
    for (int job = tid; job < ni * 64; job += 1024) {
        const int li = job >> 6;
        const int j  = job & 63;
        float acc = segp[li + 10][j];
        #pragma unroll
        for (int t = 0; t < 10; ++t) acc = fmaxf(acc, segm[li + t][j]);
        out[((size_t)k * OH + obeg + li) * OW + j] = acc;   // coalesced
    }
}

extern "C" void kernel_launch(void* const* d_in, const int* in_sizes, int n_in,
                              void* d_out, int out_size, void* d_ws, size_t ws_size,
                              hipStream_t stream) {
    const float* s = (const float*)d_in[0];
    float* out     = (float*)d_out;
    pool_fused_kernel<<<F * 2, 1024, 0, stream>>>(s, out);
}